// Round 1
// baseline (509.952 us; speedup 1.0000x reference)
//
#include <hip/hip_runtime.h>
#include <math.h>

#define B_  8
#define C_  64
#define O_  64
#define H_  128
#define W_  128
#define HW_ (H_ * W_)
#define KK_ 9

// ---------------------------------------------------------------------------
// Prep: transpose weights so inner loops over out-channel are contiguous.
//   w_off  [18][64][9] -> w_off_t [576][18]   (576 = c*9+k)
//   w_mod  [ 9][64][9] -> w_mod_t [576][ 9]
//   w_reg  [64][64][9] -> w_reg_t [576][64]
// ---------------------------------------------------------------------------
__global__ void prep_weights(const float* __restrict__ w_off,
                             const float* __restrict__ w_mod,
                             const float* __restrict__ w_reg,
                             float* __restrict__ w_off_t,
                             float* __restrict__ w_mod_t,
                             float* __restrict__ w_reg_t) {
    int t = blockIdx.x * blockDim.x + threadIdx.x;
    if (t < 18 * 576) {
        int ck = t / 18, j = t % 18;
        w_off_t[t] = w_off[j * 576 + ck];
    }
    if (t < 9 * 576) {
        int ck = t / 9, j = t % 9;
        w_mod_t[t] = w_mod[j * 576 + ck];
    }
    if (t < 64 * 576) {
        int ck = t / 64, j = t % 64;
        w_reg_t[t] = w_reg[j * 576 + ck];
    }
}

// ---------------------------------------------------------------------------
// Kernel A: 3x3 convs producing offset (18 ch, from z) and mask (9 ch, from x).
// One thread per output pixel; 27 accumulators in registers; weights are
// wave-uniform (scalar loads).
// ---------------------------------------------------------------------------
__global__ __launch_bounds__(256) void conv_offset_mask(
    const float* __restrict__ x, const float* __restrict__ z,
    const float* __restrict__ w_off_t, const float* __restrict__ b_off,
    const float* __restrict__ w_mod_t, const float* __restrict__ b_mod,
    float* __restrict__ off_out,   // [B][18][H][W]
    float* __restrict__ mask_out)  // [B][ 9][H][W]
{
    int p = blockIdx.x * blockDim.x + threadIdx.x;
    if (p >= B_ * HW_) return;
    int wo = p % W_;
    int ho = (p / W_) % H_;
    int b  = p / HW_;

    float accO[18], accM[9];
#pragma unroll
    for (int j = 0; j < 18; ++j) accO[j] = b_off[j];
#pragma unroll
    for (int j = 0; j < 9; ++j) accM[j] = b_mod[j];

    const float* zb = z + (size_t)b * C_ * HW_;
    const float* xb = x + (size_t)b * C_ * HW_;

#pragma unroll 1
    for (int c = 0; c < C_; ++c) {
        const float* zc = zb + c * HW_;
        const float* xc = xb + c * HW_;
#pragma unroll
        for (int ky = 0; ky < 3; ++ky) {
            int iy = ho + ky - 1;
            bool vy = (iy >= 0) && (iy < H_);
#pragma unroll
            for (int kx = 0; kx < 3; ++kx) {
                int ix = wo + kx - 1;
                bool v = vy && (ix >= 0) && (ix < W_);
                int k = ky * 3 + kx;
                float zv = v ? zc[iy * W_ + ix] : 0.f;
                float xv = v ? xc[iy * W_ + ix] : 0.f;
                const float* wof = w_off_t + (c * 9 + k) * 18;
#pragma unroll
                for (int j = 0; j < 18; ++j) accO[j] = fmaf(zv, wof[j], accO[j]);
                const float* wmf = w_mod_t + (c * 9 + k) * 9;
#pragma unroll
                for (int j = 0; j < 9; ++j) accM[j] = fmaf(xv, wmf[j], accM[j]);
            }
        }
    }

    int pix = ho * W_ + wo;
    float* ob = off_out + (size_t)b * 18 * HW_ + pix;
#pragma unroll
    for (int j = 0; j < 18; ++j) ob[j * HW_] = accO[j];
    float* mb = mask_out + (size_t)b * 9 * HW_ + pix;
#pragma unroll
    for (int j = 0; j < 9; ++j) mb[j * HW_] = 2.f / (1.f + expf(-accM[j]));
}

// ---------------------------------------------------------------------------
// Kernel B: modulated deformable conv. One thread per pixel, acc[64] output
// channels in VGPRs. Each (k,c) bilinear sample is computed once and feeds 64
// FMAs with wave-uniform (scalar-loaded) weights.
// PRE=true: offset/mask read from workspace, w_reg_t transposed [576][64].
// PRE=false: fully fused fallback (no workspace), w_regp is raw [64][576].
// ---------------------------------------------------------------------------
template <bool PRE>
__global__ __launch_bounds__(256) void deform_kernel(
    const float* __restrict__ x, const float* __restrict__ z,
    const float* __restrict__ off_in, const float* __restrict__ mask_in,
    const float* __restrict__ w_regp,
    const float* __restrict__ w_off, const float* __restrict__ b_off,
    const float* __restrict__ w_mod, const float* __restrict__ b_mod,
    float* __restrict__ out) {
    int p = blockIdx.x * blockDim.x + threadIdx.x;
    if (p >= B_ * HW_) return;
    int wo = p % W_;
    int ho = (p / W_) % H_;
    int b  = p / HW_;
    int pix = ho * W_ + wo;

    const float* xb = x + (size_t)b * C_ * HW_;

    float offv[18], mv[9];
    if (!PRE) {
        // inline offset/mask conv (fallback path)
        float accO[18], accM[9];
#pragma unroll
        for (int j = 0; j < 18; ++j) accO[j] = b_off[j];
#pragma unroll
        for (int j = 0; j < 9; ++j) accM[j] = b_mod[j];
        const float* zb = z + (size_t)b * C_ * HW_;
#pragma unroll 1
        for (int c = 0; c < C_; ++c) {
            const float* zc = zb + c * HW_;
            const float* xc = xb + c * HW_;
#pragma unroll
            for (int ky = 0; ky < 3; ++ky) {
                int iy = ho + ky - 1;
                bool vy = (iy >= 0) && (iy < H_);
#pragma unroll
                for (int kx = 0; kx < 3; ++kx) {
                    int ix = wo + kx - 1;
                    bool v = vy && (ix >= 0) && (ix < W_);
                    int k = ky * 3 + kx;
                    float zv = v ? zc[iy * W_ + ix] : 0.f;
                    float xv = v ? xc[iy * W_ + ix] : 0.f;
#pragma unroll
                    for (int j = 0; j < 18; ++j)
                        accO[j] = fmaf(zv, w_off[j * 576 + c * 9 + k], accO[j]);
#pragma unroll
                    for (int j = 0; j < 9; ++j)
                        accM[j] = fmaf(xv, w_mod[j * 576 + c * 9 + k], accM[j]);
                }
            }
        }
#pragma unroll
        for (int j = 0; j < 18; ++j) offv[j] = accO[j];
#pragma unroll
        for (int j = 0; j < 9; ++j) mv[j] = 2.f / (1.f + expf(-accM[j]));
    }

    float acc[64];
#pragma unroll
    for (int o = 0; o < 64; ++o) acc[o] = 0.f;

#pragma unroll 1
    for (int k = 0; k < 9; ++k) {
        int ky = k / 3, kx = k % 3;
        float dy, dx, m;
        if (PRE) {
            dy = off_in[((size_t)b * 18 + 2 * k) * HW_ + pix];
            dx = off_in[((size_t)b * 18 + 2 * k + 1) * HW_ + pix];
            m  = mask_in[((size_t)b * 9 + k) * HW_ + pix];
        } else {
            dy = offv[2 * k];
            dx = offv[2 * k + 1];
            m  = mv[k];
        }
        float py = dy + (float)(ky + ho - 1);
        float px = dx + (float)(kx + wo - 1);
        float y0f = floorf(py), x0f = floorf(px);
        float wy1 = py - y0f, wy0 = 1.f - wy1;
        float wx1 = px - x0f, wx0 = 1.f - wx1;
        int y0 = (int)y0f, x0i = (int)x0f;
        int y1 = y0 + 1, x1 = x0i + 1;
        bool vy0 = (y0 >= 0) && (y0 < H_), vy1 = (y1 >= 0) && (y1 < H_);
        bool vx0 = (x0i >= 0) && (x0i < W_), vx1 = (x1 >= 0) && (x1 < W_);
        float w00 = wy0 * wx0 * ((vy0 && vx0) ? 1.f : 0.f) * m;
        float w01 = wy0 * wx1 * ((vy0 && vx1) ? 1.f : 0.f) * m;
        float w10 = wy1 * wx0 * ((vy1 && vx0) ? 1.f : 0.f) * m;
        float w11 = wy1 * wx1 * ((vy1 && vx1) ? 1.f : 0.f) * m;
        int y0c = min(max(y0, 0), H_ - 1), y1c = min(max(y1, 0), H_ - 1);
        int x0c = min(max(x0i, 0), W_ - 1), x1c = min(max(x1, 0), W_ - 1);
        int i00 = y0c * W_ + x0c, i01 = y0c * W_ + x1c;
        int i10 = y1c * W_ + x0c, i11 = y1c * W_ + x1c;

#pragma unroll 1
        for (int c = 0; c < C_; ++c) {
            const float* xc = xb + c * HW_;
            float val = xc[i00] * w00 + xc[i01] * w01 + xc[i10] * w10 +
                        xc[i11] * w11;
            if (PRE) {
                const float* wr = w_regp + (c * 9 + k) * 64;
#pragma unroll
                for (int o = 0; o < 64; ++o) acc[o] = fmaf(val, wr[o], acc[o]);
            } else {
                const float* wr = w_regp + c * 9 + k;
#pragma unroll
                for (int o = 0; o < 64; ++o)
                    acc[o] = fmaf(val, wr[o * 576], acc[o]);
            }
        }
    }

    float* ob = out + (size_t)b * O_ * HW_ + pix;
#pragma unroll
    for (int o = 0; o < 64; ++o) ob[o * HW_] = acc[o];
}

// ---------------------------------------------------------------------------
extern "C" void kernel_launch(void* const* d_in, const int* in_sizes, int n_in,
                              void* d_out, int out_size, void* d_ws,
                              size_t ws_size, hipStream_t stream) {
    const float* x     = (const float*)d_in[0];
    const float* z     = (const float*)d_in[1];
    const float* w_off = (const float*)d_in[2];
    const float* b_off = (const float*)d_in[3];
    const float* w_mod = (const float*)d_in[4];
    const float* b_mod = (const float*)d_in[5];
    const float* w_reg = (const float*)d_in[6];
    float* out = (float*)d_out;

    const size_t nwofft = 18 * 576, nwmodt = 9 * 576, nwregt = 64 * 576;
    const size_t noff = (size_t)B_ * 18 * HW_, nmask = (size_t)B_ * 9 * HW_;
    const size_t need = (nwofft + nwmodt + nwregt + noff + nmask) * sizeof(float);

    const int npix = B_ * HW_;          // 131072
    const int nblk = (npix + 255) / 256;  // 512

    if (ws_size >= need) {
        float* w_off_t = (float*)d_ws;
        float* w_mod_t = w_off_t + nwofft;
        float* w_reg_t = w_mod_t + nwmodt;
        float* off_buf = w_reg_t + nwregt;
        float* mask_buf = off_buf + noff;
        prep_weights<<<144, 256, 0, stream>>>(w_off, w_mod, w_reg, w_off_t,
                                              w_mod_t, w_reg_t);
        conv_offset_mask<<<nblk, 256, 0, stream>>>(x, z, w_off_t, b_off,
                                                   w_mod_t, b_mod, off_buf,
                                                   mask_buf);
        deform_kernel<true><<<nblk, 256, 0, stream>>>(
            x, z, off_buf, mask_buf, w_reg_t, w_off, b_off, w_mod, b_mod, out);
    } else {
        deform_kernel<false><<<nblk, 256, 0, stream>>>(
            x, z, nullptr, nullptr, w_reg, w_off, b_off, w_mod, b_mod, out);
    }
}

// Round 2
// 344.384 us; speedup vs baseline: 1.4808x; 1.4808x over previous
//
#include <hip/hip_runtime.h>
#include <math.h>

#define B_  8
#define C_  64
#define O_  64
#define H_  128
#define W_  128
#define HW_ (H_ * W_)

// ---------------------------------------------------------------------------
// Prep: transpose weights so hot loops read contiguous, wave-uniform weights.
//   w_off  [18][64][9] -> w_off_t [576][18]   (576 = c*9+k)
//   w_mod  [ 9][64][9] -> w_mod_t [576][ 9]
//   w_reg  [64][64][9] -> w_reg_t [576][64]
// ---------------------------------------------------------------------------
__global__ void prep_weights(const float* __restrict__ w_off,
                             const float* __restrict__ w_mod,
                             const float* __restrict__ w_reg,
                             float* __restrict__ w_off_t,
                             float* __restrict__ w_mod_t,
                             float* __restrict__ w_reg_t) {
    int t = blockIdx.x * blockDim.x + threadIdx.x;
    if (t < 18 * 576) {
        int ck = t / 18, j = t % 18;
        w_off_t[t] = w_off[j * 576 + ck];
    }
    if (t < 9 * 576) {
        int ck = t / 9, j = t % 9;
        w_mod_t[t] = w_mod[j * 576 + ck];
    }
    if (t < 64 * 576) {
        int ck = t / 64, j = t % 64;
        w_reg_t[t] = w_reg[j * 576 + ck];
    }
}

// ---------------------------------------------------------------------------
// Conv v2: 27-channel 3x3 conv (18 offset from z, 9 mask from x).
// Block = 256 thr = 4 waves; tile = 64 consecutive pixels in one row.
// Wave w handles input channels [16w,16w+16): stages the 3x66 halo rows of
// its channel in private LDS (1 global load/elem instead of 9), accumulates
// partial acc[27], then cross-wave LDS reduce.
// ---------------------------------------------------------------------------
__global__ __launch_bounds__(256) void conv_offset_mask_v2(
    const float* __restrict__ x, const float* __restrict__ z,
    const float* __restrict__ w_off_t, const float* __restrict__ b_off,
    const float* __restrict__ w_mod_t, const float* __restrict__ b_mod,
    float* __restrict__ off_out,   // [B][18][H][W]
    float* __restrict__ mask_out)  // [B][ 9][H][W]
{
    __shared__ float zs[4][208];
    __shared__ float xs[4][208];
    __shared__ float red[4][64][10];

    const int lane = threadIdx.x & 63;
    const int wv = __builtin_amdgcn_readfirstlane(threadIdx.x >> 6);

    const int p0  = blockIdx.x * 64;
    const int b   = p0 / HW_;
    const int rem = p0 % HW_;     // ho*W + wx0
    const int ho  = rem / W_;
    const int wx0 = rem % W_;

    const int cbase = wv * 16;
    const float* zb = z + ((size_t)b * C_ + cbase) * HW_;
    const float* xb = x + ((size_t)b * C_ + cbase) * HW_;

    float acc[27];
#pragma unroll
    for (int j = 0; j < 27; ++j) acc[j] = 0.f;

#pragma unroll 1
    for (int ci = 0; ci < 16; ++ci) {
        const float* zc = zb + ci * HW_;
        const float* xc = xb + ci * HW_;
        // stage 3 rows x 66 cols halo (zero-padded at borders)
        for (int e = lane; e < 198; e += 64) {
            int r  = e / 66, cc = e % 66;
            int iy = ho + r - 1, ix = wx0 + cc - 1;
            bool v = (iy >= 0) && (iy < H_) && (ix >= 0) && (ix < W_);
            int idx = iy * W_ + ix;
            zs[wv][e] = v ? zc[idx] : 0.f;
            xs[wv][e] = v ? xc[idx] : 0.f;
        }
        const float* wof = w_off_t + (size_t)(cbase + ci) * 9 * 18;
        const float* wmf = w_mod_t + (size_t)(cbase + ci) * 9 * 9;
#pragma unroll
        for (int k = 0; k < 9; ++k) {
            int base = (k / 3) * 66 + (k % 3) + lane;
            float zv = zs[wv][base];
            float xv = xs[wv][base];
#pragma unroll
            for (int j = 0; j < 18; ++j)
                acc[j] = fmaf(zv, wof[k * 18 + j], acc[j]);
#pragma unroll
            for (int j = 0; j < 9; ++j)
                acc[18 + j] = fmaf(xv, wmf[k * 9 + j], acc[18 + j]);
        }
    }

    // cross-wave reduction, 3 chunks of 9 outputs
    const int pixg = rem + lane;
#pragma unroll
    for (int chunk = 0; chunk < 3; ++chunk) {
#pragma unroll
        for (int j = 0; j < 9; ++j) red[wv][lane][j] = acc[chunk * 9 + j];
        __syncthreads();
        if (wv < 3) {
#pragma unroll
            for (int j2 = 0; j2 < 3; ++j2) {
                int jl = wv * 3 + j2;
                int jo = chunk * 9 + jl;
                float s = red[0][lane][jl] + red[1][lane][jl] +
                          red[2][lane][jl] + red[3][lane][jl];
                if (jo < 18) {
                    s += b_off[jo];
                    off_out[((size_t)b * 18 + jo) * HW_ + pixg] = s;
                } else {
                    s += b_mod[jo - 18];
                    mask_out[((size_t)b * 9 + (jo - 18)) * HW_ + pixg] =
                        2.f / (1.f + expf(-s));
                }
            }
        }
        __syncthreads();
    }
}

// ---------------------------------------------------------------------------
// Deform v2: block = 256 thr = 4 waves; tile = 64 consecutive pixels.
// Wave w handles input channels [16w,16w+16), partial acc[64] (all output
// channels), weights via wave-uniform s_load; cross-wave LDS reduce.
// ---------------------------------------------------------------------------
__global__ __launch_bounds__(256) void deform_v2(
    const float* __restrict__ x,
    const float* __restrict__ off_in, const float* __restrict__ mask_in,
    const float* __restrict__ w_reg_t, float* __restrict__ out) {
    __shared__ float red[4][64][20];

    const int lane = threadIdx.x & 63;
    const int wv = __builtin_amdgcn_readfirstlane(threadIdx.x >> 6);
    const int p = blockIdx.x * 64 + lane;
    const int b = p / HW_;
    const int pix = p % HW_;
    const int ho = pix / W_;
    const int wo = pix % W_;

    const float* xb = x + ((size_t)b * C_ + wv * 16) * HW_;
    const float* offb = off_in + (size_t)b * 18 * HW_ + pix;
    const float* maskb = mask_in + (size_t)b * 9 * HW_ + pix;

    float acc[64];
#pragma unroll
    for (int o = 0; o < 64; ++o) acc[o] = 0.f;

#pragma unroll 1
    for (int k = 0; k < 9; ++k) {
        float dy = offb[(2 * k) * HW_];
        float dx = offb[(2 * k + 1) * HW_];
        float m  = maskb[k * HW_];
        float py = dy + (float)(k / 3 + ho - 1);
        float px = dx + (float)(k % 3 + wo - 1);
        float y0f = floorf(py), x0f = floorf(px);
        float wy1 = py - y0f, wy0 = 1.f - wy1;
        float wx1 = px - x0f, wx0 = 1.f - wx1;
        int y0 = (int)y0f, x0i = (int)x0f;
        int y1 = y0 + 1, x1 = x0i + 1;
        bool vy0 = (y0 >= 0) && (y0 < H_), vy1 = (y1 >= 0) && (y1 < H_);
        bool vx0 = (x0i >= 0) && (x0i < W_), vx1 = (x1 >= 0) && (x1 < W_);
        float w00 = wy0 * wx0 * ((vy0 && vx0) ? m : 0.f);
        float w01 = wy0 * wx1 * ((vy0 && vx1) ? m : 0.f);
        float w10 = wy1 * wx0 * ((vy1 && vx0) ? m : 0.f);
        float w11 = wy1 * wx1 * ((vy1 && vx1) ? m : 0.f);
        int y0c = min(max(y0, 0), H_ - 1), y1c = min(max(y1, 0), H_ - 1);
        int x0c = min(max(x0i, 0), W_ - 1), x1c = min(max(x1, 0), W_ - 1);
        int i00 = y0c * W_ + x0c, i01 = y0c * W_ + x1c;
        int i10 = y1c * W_ + x0c, i11 = y1c * W_ + x1c;

        const float* wrk = w_reg_t + ((size_t)(wv * 16) * 9 + k) * 64;
        const float* xc = xb;
#pragma unroll 1
        for (int ci = 0; ci < 16; ++ci) {
            float val = xc[i00] * w00 + xc[i01] * w01 + xc[i10] * w10 +
                        xc[i11] * w11;
            const float* wr = wrk + (size_t)ci * (9 * 64);
#pragma unroll
            for (int o = 0; o < 64; ++o) acc[o] = fmaf(val, wr[o], acc[o]);
            xc += HW_;
        }
    }

    // cross-wave reduction, 4 chunks of 16 outputs
#pragma unroll
    for (int chunk = 0; chunk < 4; ++chunk) {
#pragma unroll
        for (int j = 0; j < 16; ++j) red[wv][lane][j] = acc[chunk * 16 + j];
        __syncthreads();
#pragma unroll
        for (int j2 = 0; j2 < 4; ++j2) {
            int jl = wv * 4 + j2;
            int o = chunk * 16 + jl;
            float s = red[0][lane][jl] + red[1][lane][jl] + red[2][lane][jl] +
                      red[3][lane][jl];
            out[((size_t)b * O_ + o) * HW_ + pix] = s;
        }
        __syncthreads();
    }
}

// ---------------------------------------------------------------------------
// Fallback (no workspace): fully fused, slow but correct.
// ---------------------------------------------------------------------------
__global__ __launch_bounds__(256) void deform_fallback(
    const float* __restrict__ x, const float* __restrict__ z,
    const float* __restrict__ w_regp,
    const float* __restrict__ w_off, const float* __restrict__ b_off,
    const float* __restrict__ w_mod, const float* __restrict__ b_mod,
    float* __restrict__ out) {
    int p = blockIdx.x * blockDim.x + threadIdx.x;
    if (p >= B_ * HW_) return;
    int wo = p % W_;
    int ho = (p / W_) % H_;
    int b  = p / HW_;
    int pix = ho * W_ + wo;

    const float* xb = x + (size_t)b * C_ * HW_;

    float accO[18], accM[9];
#pragma unroll
    for (int j = 0; j < 18; ++j) accO[j] = b_off[j];
#pragma unroll
    for (int j = 0; j < 9; ++j) accM[j] = b_mod[j];
    const float* zb = z + (size_t)b * C_ * HW_;
#pragma unroll 1
    for (int c = 0; c < C_; ++c) {
        const float* zc = zb + c * HW_;
        const float* xc = xb + c * HW_;
#pragma unroll
        for (int ky = 0; ky < 3; ++ky) {
            int iy = ho + ky - 1;
            bool vy = (iy >= 0) && (iy < H_);
#pragma unroll
            for (int kx = 0; kx < 3; ++kx) {
                int ix = wo + kx - 1;
                bool v = vy && (ix >= 0) && (ix < W_);
                int k = ky * 3 + kx;
                float zv = v ? zc[iy * W_ + ix] : 0.f;
                float xv = v ? xc[iy * W_ + ix] : 0.f;
#pragma unroll
                for (int j = 0; j < 18; ++j)
                    accO[j] = fmaf(zv, w_off[j * 576 + c * 9 + k], accO[j]);
#pragma unroll
                for (int j = 0; j < 9; ++j)
                    accM[j] = fmaf(xv, w_mod[j * 576 + c * 9 + k], accM[j]);
            }
        }
    }
    float mv[9];
#pragma unroll
    for (int j = 0; j < 9; ++j) mv[j] = 2.f / (1.f + expf(-accM[j]));

    float acc[64];
#pragma unroll
    for (int o = 0; o < 64; ++o) acc[o] = 0.f;

#pragma unroll 1
    for (int k = 0; k < 9; ++k) {
        float dy = accO[2 * k], dx = accO[2 * k + 1], m = mv[k];
        float py = dy + (float)(k / 3 + ho - 1);
        float px = dx + (float)(k % 3 + wo - 1);
        float y0f = floorf(py), x0f = floorf(px);
        float wy1 = py - y0f, wy0 = 1.f - wy1;
        float wx1 = px - x0f, wx0 = 1.f - wx1;
        int y0 = (int)y0f, x0i = (int)x0f;
        int y1 = y0 + 1, x1 = x0i + 1;
        bool vy0 = (y0 >= 0) && (y0 < H_), vy1 = (y1 >= 0) && (y1 < H_);
        bool vx0 = (x0i >= 0) && (x0i < W_), vx1 = (x1 >= 0) && (x1 < W_);
        float w00 = wy0 * wx0 * ((vy0 && vx0) ? m : 0.f);
        float w01 = wy0 * wx1 * ((vy0 && vx1) ? m : 0.f);
        float w10 = wy1 * wx0 * ((vy1 && vx0) ? m : 0.f);
        float w11 = wy1 * wx1 * ((vy1 && vx1) ? m : 0.f);
        int y0c = min(max(y0, 0), H_ - 1), y1c = min(max(y1, 0), H_ - 1);
        int x0c = min(max(x0i, 0), W_ - 1), x1c = min(max(x1, 0), W_ - 1);
        int i00 = y0c * W_ + x0c, i01 = y0c * W_ + x1c;
        int i10 = y1c * W_ + x0c, i11 = y1c * W_ + x1c;
#pragma unroll 1
        for (int c = 0; c < C_; ++c) {
            const float* xc = xb + c * HW_;
            float val = xc[i00] * w00 + xc[i01] * w01 + xc[i10] * w10 +
                        xc[i11] * w11;
            const float* wr = w_regp + c * 9 + k;
#pragma unroll
            for (int o = 0; o < 64; ++o)
                acc[o] = fmaf(val, wr[o * 576], acc[o]);
        }
    }
    float* ob = out + (size_t)b * O_ * HW_ + pix;
#pragma unroll
    for (int o = 0; o < 64; ++o) ob[o * HW_] = acc[o];
}

// ---------------------------------------------------------------------------
extern "C" void kernel_launch(void* const* d_in, const int* in_sizes, int n_in,
                              void* d_out, int out_size, void* d_ws,
                              size_t ws_size, hipStream_t stream) {
    const float* x     = (const float*)d_in[0];
    const float* z     = (const float*)d_in[1];
    const float* w_off = (const float*)d_in[2];
    const float* b_off = (const float*)d_in[3];
    const float* w_mod = (const float*)d_in[4];
    const float* b_mod = (const float*)d_in[5];
    const float* w_reg = (const float*)d_in[6];
    float* out = (float*)d_out;

    const size_t nwofft = 18 * 576, nwmodt = 9 * 576, nwregt = 64 * 576;
    const size_t noff = (size_t)B_ * 18 * HW_, nmask = (size_t)B_ * 9 * HW_;
    const size_t need =
        (nwofft + nwmodt + nwregt + noff + nmask) * sizeof(float);

    const int npix = B_ * HW_;  // 131072
    const int ntile = npix / 64;  // 2048 tiles of 64 pixels

    if (ws_size >= need) {
        float* w_off_t = (float*)d_ws;
        float* w_mod_t = w_off_t + nwofft;
        float* w_reg_t = w_mod_t + nwmodt;
        float* off_buf = w_reg_t + nwregt;
        float* mask_buf = off_buf + noff;
        prep_weights<<<144, 256, 0, stream>>>(w_off, w_mod, w_reg, w_off_t,
                                              w_mod_t, w_reg_t);
        conv_offset_mask_v2<<<ntile, 256, 0, stream>>>(
            x, z, w_off_t, b_off, w_mod_t, b_mod, off_buf, mask_buf);
        deform_v2<<<ntile, 256, 0, stream>>>(x, off_buf, mask_buf, w_reg_t,
                                             out);
    } else {
        deform_fallback<<<(npix + 255) / 256, 256, 0, stream>>>(
            x, z, w_reg, w_off, b_off, w_mod, b_mod, out);
    }
}